// Round 1
// baseline (9800.178 us; speedup 1.0000x reference)
//
#include <hip/hip_runtime.h>
#include <math.h>

#define E_DIM  768
#define MQ     32      // queries per block
#define NN     64      // bank rows per tile
#define EK     64      // E chunk
#define NSPLIT 4       // bank split across blocks (occupancy)
#define BLOCK  256
#define BIGF   3.0e38f

// ---------------- branchless sorted top-3 insert (ascending) ----------------
__device__ __forceinline__ void ins3(float t[3], float v) {
    float lo0 = fminf(t[0], v);
    float hi0 = fmaxf(t[0], v);
    float lo1 = fminf(t[1], hi0);
    float hi1 = fmaxf(t[1], hi0);
    float lo2 = fminf(t[2], hi1);
    t[0] = lo0; t[1] = lo1; t[2] = lo2;
}

// ---------------- bank row norms: one wave per row ----------------
__global__ void bank_norms_k(const float* __restrict__ bank, float* __restrict__ b2, int N) {
    int gid  = blockIdx.x * blockDim.x + threadIdx.x;
    int row  = gid >> 6;
    int lane = gid & 63;
    if (row >= N) return;
    const float* p = bank + (size_t)row * E_DIM;
    float s = 0.f;
    for (int e = lane; e < E_DIM; e += 64) { float v = p[e]; s = fmaf(v, v, s); }
    #pragma unroll
    for (int off = 32; off; off >>= 1) s += __shfl_down(s, off, 64);
    if (lane == 0) b2[row] = s;
}

// ---------------- query norms: one thread per query (coalesced over hw) ----
__global__ void q_norms_k(const float* __restrict__ emb, float* __restrict__ q2, int BHW) {
    int idx = blockIdx.x * blockDim.x + threadIdx.x;
    if (idx >= BHW) return;
    int b  = idx >> 10;        // /1024
    int hw = idx & 1023;
    const float* p = emb + (size_t)b * E_DIM * 1024 + hw;
    float s = 0.f;
    #pragma unroll 8
    for (int e = 0; e < E_DIM; e++) { float v = p[(size_t)e << 10]; s = fmaf(v, v, s); }
    q2[idx] = s;
}

// ---------------- main fused distance + top-3 kernel ----------------
// grid = (BHW/MQ) * NSPLIT blocks of 256 threads.
// Each block: MQ consecutive queries (same image) vs one N-split of the bank.
__global__ __launch_bounds__(BLOCK, 4)
void knn_main_k(const float* __restrict__ emb, const float* __restrict__ bank,
                const float* __restrict__ q2g, const float* __restrict__ b2g,
                float* __restrict__ cand, int BHW, int Nbank) {
    // e-major LDS: reads in the FMA loop are broadcast (qs) / 2-way (bs) => free
    __shared__ float qs[EK][MQ];
    __shared__ float bs[EK][NN + 1];
    __shared__ float mrg[MQ][16 * 3];

    const int tid = threadIdx.x;
    const int qt  = blockIdx.x / NSPLIT;
    const int sp  = blockIdx.x % NSPLIT;
    const int qbase = qt * MQ;
    const int img   = qbase >> 10;       // image index (MQ=32 divides 1024)
    const int hw0   = qbase & 1023;

    const int nchunk = (Nbank + NSPLIT - 1) / NSPLIT;
    const int nstart = sp * nchunk;
    const int nend   = min(Nbank, nstart + nchunk);

    const int tn = tid & 15;             // covers n = tile + tn*4 .. +3
    const int tm = tid >> 4;             // covers m = tm*2, tm*2+1
    const int m0 = tm * 2;

    const float q2m0 = q2g[qbase + m0];
    const float q2m1 = q2g[qbase + m0 + 1];

    float t3[2][3];
    t3[0][0] = t3[0][1] = t3[0][2] = BIGF;
    t3[1][0] = t3[1][1] = t3[1][2] = BIGF;

    const float* embB = emb + (size_t)img * E_DIM * 1024 + hw0;

    for (int n0 = nstart; n0 < nend; n0 += NN) {
        float acc[2][4] = {{0.f,0.f,0.f,0.f},{0.f,0.f,0.f,0.f}};

        for (int e0 = 0; e0 < E_DIM; e0 += EK) {
            __syncthreads();
            // stage q tile: EK x MQ (lanes along m -> coalesced 128B rows)
            #pragma unroll
            for (int k = tid; k < EK * MQ; k += BLOCK) {
                int ee = k >> 5, mm = k & 31;
                qs[ee][mm] = embB[(size_t)(e0 + ee) * 1024 + mm];
            }
            // stage bank tile: lanes along e -> coalesced rows; padded write conflict-free
            #pragma unroll
            for (int k = tid; k < NN * EK; k += BLOCK) {
                int nn = k >> 6, ee = k & 63;
                int n  = n0 + nn;
                bs[ee][nn] = (n < nend) ? bank[(size_t)n * E_DIM + e0 + ee] : 0.f;
            }
            __syncthreads();

            #pragma unroll
            for (int e = 0; e < EK; e++) {
                float qa = qs[e][m0];
                float qb = qs[e][m0 + 1];
                float b0 = bs[e][tn * 4 + 0];
                float b1 = bs[e][tn * 4 + 1];
                float b2v = bs[e][tn * 4 + 2];
                float b3 = bs[e][tn * 4 + 3];
                acc[0][0] = fmaf(qa, b0, acc[0][0]);
                acc[0][1] = fmaf(qa, b1, acc[0][1]);
                acc[0][2] = fmaf(qa, b2v, acc[0][2]);
                acc[0][3] = fmaf(qa, b3, acc[0][3]);
                acc[1][0] = fmaf(qb, b0, acc[1][0]);
                acc[1][1] = fmaf(qb, b1, acc[1][1]);
                acc[1][2] = fmaf(qb, b2v, acc[1][2]);
                acc[1][3] = fmaf(qb, b3, acc[1][3]);
            }
        }
        // distances + top-3 update
        #pragma unroll
        for (int j = 0; j < 4; j++) {
            int n = n0 + tn * 4 + j;
            float bn = (n < nend) ? b2g[n] : BIGF;
            float d0 = q2m0 + bn - 2.f * acc[0][j];
            float d1 = q2m1 + bn - 2.f * acc[1][j];
            ins3(t3[0], d0);
            ins3(t3[1], d1);
        }
    }

    // merge 16 partial top-3s per query
    __syncthreads();
    #pragma unroll
    for (int r = 0; r < 3; r++) {
        mrg[m0][tn * 3 + r]     = t3[0][r];
        mrg[m0 + 1][tn * 3 + r] = t3[1][r];
    }
    __syncthreads();
    if (tid < MQ) {
        float best[3] = {BIGF, BIGF, BIGF};
        #pragma unroll 4
        for (int k = 0; k < 48; k++) ins3(best, mrg[tid][k]);
        float* o = cand + ((size_t)sp * BHW + qbase + tid) * 3;
        o[0] = best[0]; o[1] = best[1]; o[2] = best[2];
    }
}

// ---------------- merge splits -> scores ----------------
__global__ void scores_k(const float* __restrict__ cand, float* __restrict__ scores, int BHW) {
    int idx = blockIdx.x * blockDim.x + threadIdx.x;
    if (idx >= BHW) return;
    float best[3] = {BIGF, BIGF, BIGF};
    for (int sp = 0; sp < NSPLIT; sp++) {
        const float* c = cand + ((size_t)sp * BHW + idx) * 3;
        ins3(best, c[0]); ins3(best, c[1]); ins3(best, c[2]);
    }
    float s = (sqrtf(fmaxf(best[0], 1e-12f)) +
               sqrtf(fmaxf(best[1], 1e-12f)) +
               sqrtf(fmaxf(best[2], 1e-12f))) * (1.f / 3.f);
    scores[idx] = s;
}

// ---------------- bilinear x16 upsample, half-pixel, edge clamp ----------------
__global__ void upsample_k(const float* __restrict__ scores, float* __restrict__ out, int total) {
    int idx = blockIdx.x * blockDim.x + threadIdx.x;
    if (idx >= total) return;
    int x = idx & 511;
    int y = (idx >> 9) & 511;
    int b = idx >> 18;
    float sx = (x + 0.5f) * (1.f / 16.f) - 0.5f;
    float sy = (y + 0.5f) * (1.f / 16.f) - 0.5f;
    int x0 = (int)floorf(sx);
    int y0 = (int)floorf(sy);
    float wx = sx - (float)x0;
    float wy = sy - (float)y0;
    int x0c = min(max(x0, 0), 31), x1c = min(max(x0 + 1, 0), 31);
    int y0c = min(max(y0, 0), 31), y1c = min(max(y0 + 1, 0), 31);
    const float* sb = scores + (size_t)b * 1024;
    float v00 = sb[y0c * 32 + x0c], v01 = sb[y0c * 32 + x1c];
    float v10 = sb[y1c * 32 + x0c], v11 = sb[y1c * 32 + x1c];
    float v0 = v00 + wx * (v01 - v00);
    float v1 = v10 + wx * (v11 - v10);
    out[idx] = v0 + wy * (v1 - v0);
}

extern "C" void kernel_launch(void* const* d_in, const int* in_sizes, int n_in,
                              void* d_out, int out_size, void* d_ws, size_t ws_size,
                              hipStream_t stream) {
    const float* emb  = (const float*)d_in[0];
    const float* bank = (const float*)d_in[1];
    const int BHW   = in_sizes[0] / E_DIM;   // 8192
    const int Nbank = in_sizes[1] / E_DIM;   // 20000

    float* ws     = (float*)d_ws;
    float* q2     = ws;                                   // BHW
    float* b2     = q2 + BHW;                             // Nbank
    float* cand   = b2 + Nbank;                           // NSPLIT*BHW*3
    float* scores = cand + (size_t)NSPLIT * BHW * 3;      // BHW
    float* out    = (float*)d_out;

    hipLaunchKernelGGL(q_norms_k, dim3((BHW + 255) / 256), dim3(256), 0, stream,
                       emb, q2, BHW);
    hipLaunchKernelGGL(bank_norms_k, dim3((Nbank * 64 + 255) / 256), dim3(256), 0, stream,
                       bank, b2, Nbank);
    hipLaunchKernelGGL(knn_main_k, dim3((BHW / MQ) * NSPLIT), dim3(BLOCK), 0, stream,
                       emb, bank, q2, b2, cand, BHW, Nbank);
    hipLaunchKernelGGL(scores_k, dim3((BHW + 255) / 256), dim3(256), 0, stream,
                       cand, scores, BHW);
    hipLaunchKernelGGL(upsample_k, dim3((out_size + 255) / 256), dim3(256), 0, stream,
                       scores, out, out_size);
}

// Round 2
// 736.701 us; speedup vs baseline: 13.3028x; 13.3028x over previous
//
#include <hip/hip_runtime.h>
#include <math.h>

#define KD     768     // embedding dim
#define MT     128     // M tile (queries)
#define NT     128     // N tile (bank rows)
#define BK     64      // K chunk
#define NSPLIT 16      // bank splits per M tile
#define BIGF   3.0e38f

typedef __attribute__((ext_vector_type(8))) short bf16x8;
typedef __attribute__((ext_vector_type(4))) float f32x4;

__device__ __forceinline__ unsigned short f2bf(float f) {
    unsigned u = __float_as_uint(f);
    u += 0x7fffu + ((u >> 16) & 1u);          // round-to-nearest-even
    return (unsigned short)(u >> 16);
}
__device__ __forceinline__ float bf2f(unsigned short h) {
    return __uint_as_float(((unsigned)h) << 16);
}
__device__ __forceinline__ void ins3(float* t, float v) {
    float lo0 = fminf(t[0], v);
    float hi0 = fmaxf(t[0], v);
    float lo1 = fminf(t[1], hi0);
    float hi1 = fmaxf(t[1], hi0);
    float lo2 = fminf(t[2], hi1);
    t[0] = lo0; t[1] = lo1; t[2] = lo2;
}
__device__ __forceinline__ void async16(unsigned short* lds, const unsigned short* g) {
    __builtin_amdgcn_global_load_lds(
        (const __attribute__((address_space(1))) unsigned int*)g,
        (__attribute__((address_space(3))) unsigned int*)lds, 16, 0, 0);
}

// ---- emb [B][768][1024] -> qbf [B*1024][768] bf16 (LDS tile transpose) ----
__global__ void q_prep_k(const float* __restrict__ emb, unsigned short* __restrict__ qbf) {
    __shared__ float s[64][65];
    int b   = blockIdx.x >> 4;
    int hw0 = (blockIdx.x & 15) * 64;
    const float* src = emb + (size_t)b * KD * 1024;
    for (int e0 = 0; e0 < KD; e0 += 64) {
        __syncthreads();
        #pragma unroll
        for (int i = 0; i < 16; ++i) {
            int idx = threadIdx.x + i * 256;      // 0..4095
            int ee = idx >> 6, hh = idx & 63;
            s[ee][hh] = src[(size_t)(e0 + ee) * 1024 + hw0 + hh];
        }
        __syncthreads();
        #pragma unroll
        for (int i = 0; i < 16; ++i) {
            int idx = threadIdx.x + i * 256;
            int qq = idx >> 6, ee = idx & 63;
            qbf[((size_t)b * 1024 + hw0 + qq) * KD + e0 + ee] = f2bf(s[ee][qq]);
        }
    }
}

// ---- q norms from bf16-rounded values: one wave per query ----
__global__ void q2_k(const unsigned short* __restrict__ qbf, float* __restrict__ q2, int Q) {
    int gid = blockIdx.x * 256 + threadIdx.x;
    int q = gid >> 6, lane = gid & 63;
    if (q >= Q) return;
    float s = 0.f;
    #pragma unroll
    for (int i = 0; i < KD / 64; ++i) {
        float v = bf2f(qbf[(size_t)q * KD + lane + i * 64]);
        s = fmaf(v, v, s);
    }
    #pragma unroll
    for (int off = 32; off; off >>= 1) s += __shfl_down(s, off, 64);
    if (lane == 0) q2[q] = s;
}

// ---- bank -> bbf bf16 (zero-padded rows) + b2 norms (BIGF pad) ----
__global__ void bank_prep_k(const float* __restrict__ bank, unsigned short* __restrict__ bbf,
                            float* __restrict__ b2, int N, int Npad) {
    int gid = blockIdx.x * 256 + threadIdx.x;
    int row = gid >> 6, lane = gid & 63;
    if (row >= Npad) return;
    if (row < N) {
        float s = 0.f;
        #pragma unroll
        for (int i = 0; i < KD / 64; ++i) {
            float v = bank[(size_t)row * KD + lane + i * 64];
            unsigned short u = f2bf(v);
            float vb = bf2f(u);
            s = fmaf(vb, vb, s);
            bbf[(size_t)row * KD + lane + i * 64] = u;
        }
        #pragma unroll
        for (int off = 32; off; off >>= 1) s += __shfl_down(s, off, 64);
        if (lane == 0) b2[row] = s;
    } else {
        #pragma unroll
        for (int i = 0; i < KD / 64; ++i) bbf[(size_t)row * KD + lane + i * 64] = 0;
        if (lane == 0) b2[row] = BIGF;
    }
}

// ---- main: bf16 MFMA distance GEMM + fused per-row top-3 ----
// grid = (Q/MT) * NSPLIT. Each block: 128 queries vs round-robin N tiles.
__global__ __launch_bounds__(256, 2)
void knn_mfma_k(const unsigned short* __restrict__ qbf, const unsigned short* __restrict__ bbf,
                const float* __restrict__ q2g, const float* __restrict__ b2g,
                float* __restrict__ cand, int ntiles, int Q) {
    __shared__ union {
        unsigned short stage[2][MT * BK];   // A tile | B tile, XOR-swizzled
        float mrg[MT][97];                  // top-3 merge scratch (pad->odd stride)
    } sm;

    const int tid  = threadIdx.x;
    const int lane = tid & 63;
    const int quad = lane >> 4;
    const int l15  = lane & 15;
    const int wid  = tid >> 6;
    const int wm   = wid & 1;
    const int wn   = wid >> 1;

    const int sp    = blockIdx.x & (NSPLIT - 1);
    const int mt    = blockIdx.x / NSPLIT;
    const int Mbase = mt * MT;

    float q2c[16];
    #pragma unroll
    for (int mi = 0; mi < 4; ++mi)
        #pragma unroll
        for (int r = 0; r < 4; ++r)
            q2c[mi * 4 + r] = q2g[Mbase + 64 * wm + 16 * mi + 4 * quad + r];

    float top3[48];
    #pragma unroll
    for (int i = 0; i < 48; ++i) top3[i] = BIGF;

    const int xr = l15 & 7;

    for (int nt = sp; nt < ntiles; nt += NSPLIT) {
        const size_t nbase = (size_t)nt * NT;
        f32x4 acc[4][4];
        #pragma unroll
        for (int a = 0; a < 4; ++a)
            #pragma unroll
            for (int b = 0; b < 4; ++b) acc[a][b] = (f32x4){0.f, 0.f, 0.f, 0.f};

        const unsigned short* gA = qbf + (size_t)Mbase * KD;
        const unsigned short* gB = bbf + nbase * KD;

        for (int kc = 0; kc < KD / BK; ++kc) {
            const int k0 = kc * BK;
            __syncthreads();
            // stage A: 1024 slots of 16B; slot s=(m,g) holds global k-group g^(m&7)
            #pragma unroll
            for (int i = 0; i < 4; ++i) {
                int s = tid + i * 256;
                int m = s >> 3, g = s & 7;
                int G = g ^ (m & 7);
                async16(&sm.stage[0][s * 8], gA + (size_t)m * KD + k0 + G * 8);
            }
            #pragma unroll
            for (int i = 0; i < 4; ++i) {
                int s = tid + i * 256;
                int m = s >> 3, g = s & 7;
                int G = g ^ (m & 7);
                async16(&sm.stage[1][s * 8], gB + (size_t)m * KD + k0 + G * 8);
            }
            __syncthreads();
            #pragma unroll
            for (int ks = 0; ks < 2; ++ks) {
                bf16x8 af[4], bfr[4];
                const int Gk = ks * 4 + quad;
                const int col = ((Gk ^ xr) << 3);
                #pragma unroll
                for (int mi = 0; mi < 4; ++mi) {
                    int row = 64 * wm + 16 * mi + l15;
                    af[mi] = *(const bf16x8*)&sm.stage[0][row * BK + col];
                }
                #pragma unroll
                for (int ni = 0; ni < 4; ++ni) {
                    int row = 64 * wn + 16 * ni + l15;
                    bfr[ni] = *(const bf16x8*)&sm.stage[1][row * BK + col];
                }
                #pragma unroll
                for (int mi = 0; mi < 4; ++mi)
                    #pragma unroll
                    for (int ni = 0; ni < 4; ++ni)
                        acc[mi][ni] = __builtin_amdgcn_mfma_f32_16x16x32_bf16(
                            af[mi], bfr[ni], acc[mi][ni], 0, 0, 0);
            }
        }
        // epilogue: d2 = q2 + b2 - 2*dot, per-row top3 (C layout: col=l15, row=4*quad+reg)
        #pragma unroll
        for (int ni = 0; ni < 4; ++ni) {
            float b2v = b2g[nbase + 64 * wn + 16 * ni + l15];
            #pragma unroll
            for (int mi = 0; mi < 4; ++mi)
                #pragma unroll
                for (int r = 0; r < 4; ++r) {
                    float d2 = q2c[mi * 4 + r] + b2v - 2.0f * acc[mi][ni][r];
                    ins3(&top3[(mi * 4 + r) * 3], d2);
                }
        }
    }

    // cross-lane merge: 32 partials (2 waves x 16 cols) per query row
    __syncthreads();
    #pragma unroll
    for (int mi = 0; mi < 4; ++mi)
        #pragma unroll
        for (int r = 0; r < 4; ++r) {
            int row_l = 64 * wm + 16 * mi + 4 * quad + r;
            int slot  = wn * 16 + l15;
            #pragma unroll
            for (int j = 0; j < 3; ++j)
                sm.mrg[row_l][slot * 3 + j] = top3[(mi * 4 + r) * 3 + j];
        }
    __syncthreads();
    if (tid < MT) {
        float best[3] = {BIGF, BIGF, BIGF};
        #pragma unroll 8
        for (int k = 0; k < 96; ++k) ins3(best, sm.mrg[tid][k]);
        float* o = cand + ((size_t)sp * Q + Mbase + tid) * 3;
        o[0] = best[0]; o[1] = best[1]; o[2] = best[2];
    }
}

// ---- merge splits -> mean sqrt distance ----
__global__ void scores_k(const float* __restrict__ cand, float* __restrict__ scores, int Q) {
    int idx = blockIdx.x * blockDim.x + threadIdx.x;
    if (idx >= Q) return;
    float best[3] = {BIGF, BIGF, BIGF};
    for (int sp = 0; sp < NSPLIT; sp++) {
        const float* c = cand + ((size_t)sp * Q + idx) * 3;
        ins3(best, c[0]); ins3(best, c[1]); ins3(best, c[2]);
    }
    float s = (sqrtf(fmaxf(best[0], 1e-12f)) +
               sqrtf(fmaxf(best[1], 1e-12f)) +
               sqrtf(fmaxf(best[2], 1e-12f))) * (1.f / 3.f);
    scores[idx] = s;
}

// ---- bilinear x16 upsample, half-pixel, edge clamp ----
__global__ void upsample_k(const float* __restrict__ scores, float* __restrict__ out, int total) {
    int idx = blockIdx.x * blockDim.x + threadIdx.x;
    if (idx >= total) return;
    int x = idx & 511;
    int y = (idx >> 9) & 511;
    int b = idx >> 18;
    float sx = (x + 0.5f) * (1.f / 16.f) - 0.5f;
    float sy = (y + 0.5f) * (1.f / 16.f) - 0.5f;
    int x0 = (int)floorf(sx);
    int y0 = (int)floorf(sy);
    float wx = sx - (float)x0;
    float wy = sy - (float)y0;
    int x0c = min(max(x0, 0), 31), x1c = min(max(x0 + 1, 0), 31);
    int y0c = min(max(y0, 0), 31), y1c = min(max(y0 + 1, 0), 31);
    const float* sb = scores + (size_t)b * 1024;
    float v00 = sb[y0c * 32 + x0c], v01 = sb[y0c * 32 + x1c];
    float v10 = sb[y1c * 32 + x0c], v11 = sb[y1c * 32 + x1c];
    float v0 = v00 + wx * (v01 - v00);
    float v1 = v10 + wx * (v11 - v10);
    out[idx] = v0 + wy * (v1 - v0);
}

extern "C" void kernel_launch(void* const* d_in, const int* in_sizes, int n_in,
                              void* d_out, int out_size, void* d_ws, size_t ws_size,
                              hipStream_t stream) {
    const float* emb  = (const float*)d_in[0];
    const float* bank = (const float*)d_in[1];
    const int Q      = in_sizes[0] / KD;             // 8192
    const int B      = Q / 1024;                     // 8
    const int Nbank  = in_sizes[1] / KD;             // 20000
    const int ntiles = (Nbank + NT - 1) / NT;        // 157
    const int Npad   = ntiles * NT;                  // 20096
    const int Mtiles = Q / MT;                       // 64

    // workspace layout
    unsigned short* qbf = (unsigned short*)d_ws;                       // Q*KD
    unsigned short* bbf = qbf + (size_t)Q * KD;                        // Npad*KD
    float* fbase  = (float*)(bbf + (size_t)Npad * KD);
    float* q2     = fbase;                                             // Q
    float* b2     = q2 + Q;                                            // Npad
    float* cand   = b2 + Npad;                                         // NSPLIT*Q*3
    float* scores = cand + (size_t)NSPLIT * Q * 3;                     // Q
    float* out    = (float*)d_out;

    hipLaunchKernelGGL(q_prep_k, dim3(B * 16), dim3(256), 0, stream, emb, qbf);
    hipLaunchKernelGGL(bank_prep_k, dim3((Npad * 64 + 255) / 256), dim3(256), 0, stream,
                       bank, bbf, b2, Nbank, Npad);
    hipLaunchKernelGGL(q2_k, dim3((Q * 64 + 255) / 256), dim3(256), 0, stream, qbf, q2, Q);
    hipLaunchKernelGGL(knn_mfma_k, dim3(Mtiles * NSPLIT), dim3(256), 0, stream,
                       qbf, bbf, q2, b2, cand, ntiles, Q);
    hipLaunchKernelGGL(scores_k, dim3((Q + 255) / 256), dim3(256), 0, stream, cand, scores, Q);
    hipLaunchKernelGGL(upsample_k, dim3((out_size + 255) / 256), dim3(256), 0, stream,
                       scores, out, out_size);
}

// Round 3
// 703.559 us; speedup vs baseline: 13.9294x; 1.0471x over previous
//
#include <hip/hip_runtime.h>
#include <math.h>

#define KD     768     // embedding dim
#define MT     128     // M tile (queries)
#define NT     128     // N tile (bank rows)
#define BK     64      // K chunk
#define NSPLIT 16      // bank splits per M tile
#define BIGF   3.0e38f

typedef __attribute__((ext_vector_type(8))) short bf16x8;
typedef __attribute__((ext_vector_type(4))) float f32x4;

__device__ __forceinline__ unsigned short f2bf(float f) {
    unsigned u = __float_as_uint(f);
    u += 0x7fffu + ((u >> 16) & 1u);          // round-to-nearest-even
    return (unsigned short)(u >> 16);
}
__device__ __forceinline__ float bf2f(unsigned short h) {
    return __uint_as_float(((unsigned)h) << 16);
}
__device__ __forceinline__ void ins3(float* t, float v) {
    float lo0 = fminf(t[0], v);
    float hi0 = fmaxf(t[0], v);
    float lo1 = fminf(t[1], hi0);
    float hi1 = fmaxf(t[1], hi0);
    float lo2 = fminf(t[2], hi1);
    t[0] = lo0; t[1] = lo1; t[2] = lo2;
}
__device__ __forceinline__ void async16(unsigned short* lds, const unsigned short* g) {
    __builtin_amdgcn_global_load_lds(
        (const __attribute__((address_space(1))) unsigned int*)g,
        (__attribute__((address_space(3))) unsigned int*)lds, 16, 0, 0);
}

// ---- emb [B][768][1024] -> qbf [B*1024][768] bf16 (LDS tile transpose) ----
__global__ void q_prep_k(const float* __restrict__ emb, unsigned short* __restrict__ qbf) {
    __shared__ float s[64][65];
    int b   = blockIdx.x >> 4;
    int hw0 = (blockIdx.x & 15) * 64;
    const float* src = emb + (size_t)b * KD * 1024;
    for (int e0 = 0; e0 < KD; e0 += 64) {
        __syncthreads();
        #pragma unroll
        for (int i = 0; i < 16; ++i) {
            int idx = threadIdx.x + i * 256;      // 0..4095
            int ee = idx >> 6, hh = idx & 63;
            s[ee][hh] = src[(size_t)(e0 + ee) * 1024 + hw0 + hh];
        }
        __syncthreads();
        #pragma unroll
        for (int i = 0; i < 16; ++i) {
            int idx = threadIdx.x + i * 256;
            int qq = idx >> 6, ee = idx & 63;
            qbf[((size_t)b * 1024 + hw0 + qq) * KD + e0 + ee] = f2bf(s[ee][qq]);
        }
    }
}

// ---- bank -> bbf bf16 (zero-padded) + b2 norms (BIGF pad) + q2 norms ----
// rows [0, Npad) = bank path; rows [Npad, Npad+Q) = query-norm path (reads qbf).
__global__ void prep2_k(const float* __restrict__ bank, const unsigned short* __restrict__ qbf,
                        unsigned short* __restrict__ bbf, float* __restrict__ b2,
                        float* __restrict__ q2, int N, int Npad, int Q) {
    int gid = blockIdx.x * 256 + threadIdx.x;
    int row = gid >> 6, lane = gid & 63;
    if (row < Npad) {
        if (row < N) {
            float s = 0.f;
            #pragma unroll
            for (int i = 0; i < KD / 64; ++i) {
                float v = bank[(size_t)row * KD + lane + i * 64];
                unsigned short u = f2bf(v);
                float vb = bf2f(u);
                s = fmaf(vb, vb, s);
                bbf[(size_t)row * KD + lane + i * 64] = u;
            }
            #pragma unroll
            for (int off = 32; off; off >>= 1) s += __shfl_down(s, off, 64);
            if (lane == 0) b2[row] = s;
        } else {
            #pragma unroll
            for (int i = 0; i < KD / 64; ++i) bbf[(size_t)row * KD + lane + i * 64] = 0;
            if (lane == 0) b2[row] = BIGF;
        }
    } else {
        int q = row - Npad;
        if (q < Q) {
            float s = 0.f;
            #pragma unroll
            for (int i = 0; i < KD / 64; ++i) {
                float v = bf2f(qbf[(size_t)q * KD + lane + i * 64]);
                s = fmaf(v, v, s);
            }
            #pragma unroll
            for (int off = 32; off; off >>= 1) s += __shfl_down(s, off, 64);
            if (lane == 0) q2[q] = s;
        }
    }
}

// ---- main: bf16 MFMA distance GEMM + fused per-row top-3 ----
// grid = 1024. sp bits {0,1,2,8} keep XCD L2 locality (each XCD sees 2 bank
// slices ~= 3.9 MB) while mixing 2 different sps per CU (work balance).
__global__ __launch_bounds__(256, 4)
void knn_mfma_k(const unsigned short* __restrict__ qbf, const unsigned short* __restrict__ bbf,
                const float* __restrict__ q2g, const float* __restrict__ b2g,
                float* __restrict__ cand, int ntiles, int Q) {
    __shared__ unsigned short stage[2][MT * BK];   // A tile | B tile, XOR-swizzled (32768 B)

    const int tid  = threadIdx.x;
    const int lane = tid & 63;
    const int quad = lane >> 4;
    const int l15  = lane & 15;
    const int wid  = tid >> 6;
    const int wm   = wid & 1;
    const int wn   = wid >> 1;

    const int bx    = blockIdx.x;
    const int sp    = (bx & 7) | (((bx >> 8) & 1) << 3);
    const int mt    = ((bx >> 3) & 31) | (((bx >> 9) & 1) << 5);
    const int Mbase = mt * MT;

    float q2c[16];
    #pragma unroll
    for (int mi = 0; mi < 4; ++mi)
        #pragma unroll
        for (int r = 0; r < 4; ++r)
            q2c[mi * 4 + r] = q2g[Mbase + 64 * wm + 16 * mi + 4 * quad + r];

    float top3[48];
    #pragma unroll
    for (int i = 0; i < 48; ++i) top3[i] = BIGF;

    const int xr = l15 & 7;

    for (int nt = sp; nt < ntiles; nt += NSPLIT) {
        const size_t nbase = (size_t)nt * NT;
        f32x4 acc[4][4];
        #pragma unroll
        for (int a = 0; a < 4; ++a)
            #pragma unroll
            for (int b = 0; b < 4; ++b) acc[a][b] = (f32x4){0.f, 0.f, 0.f, 0.f};

        const unsigned short* gA = qbf + (size_t)Mbase * KD;
        const unsigned short* gB = bbf + nbase * KD;

        for (int kc = 0; kc < KD / BK; ++kc) {
            const int k0 = kc * BK;
            __syncthreads();
            // stage A/B: 1024 slots of 16B each; slot s=(m,g) holds k-group g^(m&7)
            #pragma unroll
            for (int i = 0; i < 4; ++i) {
                int s = tid + i * 256;
                int m = s >> 3, g = s & 7;
                int G = g ^ (m & 7);
                async16(&stage[0][s * 8], gA + (size_t)m * KD + k0 + G * 8);
            }
            #pragma unroll
            for (int i = 0; i < 4; ++i) {
                int s = tid + i * 256;
                int m = s >> 3, g = s & 7;
                int G = g ^ (m & 7);
                async16(&stage[1][s * 8], gB + (size_t)m * KD + k0 + G * 8);
            }
            __syncthreads();
            #pragma unroll
            for (int ks = 0; ks < 2; ++ks) {
                bf16x8 af[4], bfr[4];
                const int Gk = ks * 4 + quad;
                const int col = ((Gk ^ xr) << 3);
                #pragma unroll
                for (int mi = 0; mi < 4; ++mi) {
                    int row = 64 * wm + 16 * mi + l15;
                    af[mi] = *(const bf16x8*)&stage[0][row * BK + col];
                }
                #pragma unroll
                for (int ni = 0; ni < 4; ++ni) {
                    int row = 64 * wn + 16 * ni + l15;
                    bfr[ni] = *(const bf16x8*)&stage[1][row * BK + col];
                }
                #pragma unroll
                for (int mi = 0; mi < 4; ++mi)
                    #pragma unroll
                    for (int ni = 0; ni < 4; ++ni)
                        acc[mi][ni] = __builtin_amdgcn_mfma_f32_16x16x32_bf16(
                            af[mi], bfr[ni], acc[mi][ni], 0, 0, 0);
            }
        }
        // epilogue: d2 = q2 + b2 - 2*dot, per-row top3 (C layout: col=l15, row=4*quad+reg)
        #pragma unroll
        for (int ni = 0; ni < 4; ++ni) {
            float b2v = b2g[nbase + 64 * wn + 16 * ni + l15];
            #pragma unroll
            for (int mi = 0; mi < 4; ++mi)
                #pragma unroll
                for (int r = 0; r < 4; ++r) {
                    float d2 = q2c[mi * 4 + r] + b2v - 2.0f * acc[mi][ni][r];
                    ins3(&top3[(mi * 4 + r) * 3], d2);
                }
        }
    }

    // merge the 16 column-partials per query row via shfl_xor butterfly
    // (xor masks 1,2,4,8 stay within each 16-lane group)
    #pragma unroll
    for (int mi = 0; mi < 4; ++mi)
        #pragma unroll
        for (int r = 0; r < 4; ++r) {
            float a0 = top3[(mi * 4 + r) * 3 + 0];
            float a1 = top3[(mi * 4 + r) * 3 + 1];
            float a2 = top3[(mi * 4 + r) * 3 + 2];
            #pragma unroll
            for (int off = 1; off < 16; off <<= 1) {
                float b0 = __shfl_xor(a0, off, 64);
                float b1 = __shfl_xor(a1, off, 64);
                float b2v = __shfl_xor(a2, off, 64);
                float t[3] = {a0, a1, a2};
                ins3(t, b0); ins3(t, b1); ins3(t, b2v);
                a0 = t[0]; a1 = t[1]; a2 = t[2];
            }
            if (l15 == 0) {
                int row = Mbase + 64 * wm + 16 * mi + 4 * quad + r;
                float* o = cand + ((size_t)(sp * 2 + wn) * Q + row) * 3;
                o[0] = a0; o[1] = a1; o[2] = a2;
            }
        }
}

// ---- merge 32 split-partials -> mean sqrt distance ----
__global__ void scores_k(const float* __restrict__ cand, float* __restrict__ scores, int Q) {
    int idx = blockIdx.x * blockDim.x + threadIdx.x;
    if (idx >= Q) return;
    float best[3] = {BIGF, BIGF, BIGF};
    for (int sp = 0; sp < NSPLIT * 2; sp++) {
        const float* c = cand + ((size_t)sp * Q + idx) * 3;
        ins3(best, c[0]); ins3(best, c[1]); ins3(best, c[2]);
    }
    float s = (sqrtf(fmaxf(best[0], 1e-12f)) +
               sqrtf(fmaxf(best[1], 1e-12f)) +
               sqrtf(fmaxf(best[2], 1e-12f))) * (1.f / 3.f);
    scores[idx] = s;
}

// ---- bilinear x16 upsample, half-pixel, edge clamp ----
__global__ void upsample_k(const float* __restrict__ scores, float* __restrict__ out, int total) {
    int idx = blockIdx.x * blockDim.x + threadIdx.x;
    if (idx >= total) return;
    int x = idx & 511;
    int y = (idx >> 9) & 511;
    int b = idx >> 18;
    float sx = (x + 0.5f) * (1.f / 16.f) - 0.5f;
    float sy = (y + 0.5f) * (1.f / 16.f) - 0.5f;
    int x0 = (int)floorf(sx);
    int y0 = (int)floorf(sy);
    float wx = sx - (float)x0;
    float wy = sy - (float)y0;
    int x0c = min(max(x0, 0), 31), x1c = min(max(x0 + 1, 0), 31);
    int y0c = min(max(y0, 0), 31), y1c = min(max(y0 + 1, 0), 31);
    const float* sb = scores + (size_t)b * 1024;
    float v00 = sb[y0c * 32 + x0c], v01 = sb[y0c * 32 + x1c];
    float v10 = sb[y1c * 32 + x0c], v11 = sb[y1c * 32 + x1c];
    float v0 = v00 + wx * (v01 - v00);
    float v1 = v10 + wx * (v11 - v10);
    out[idx] = v0 + wy * (v1 - v0);
}

extern "C" void kernel_launch(void* const* d_in, const int* in_sizes, int n_in,
                              void* d_out, int out_size, void* d_ws, size_t ws_size,
                              hipStream_t stream) {
    const float* emb  = (const float*)d_in[0];
    const float* bank = (const float*)d_in[1];
    const int Q      = in_sizes[0] / KD;             // 8192
    const int B      = Q / 1024;                     // 8
    const int Nbank  = in_sizes[1] / KD;             // 20000
    const int ntiles = (Nbank + NT - 1) / NT;        // 157
    const int Npad   = ntiles * NT;                  // 20096
    const int Mtiles = Q / MT;                       // 64

    // workspace layout
    unsigned short* qbf = (unsigned short*)d_ws;                       // Q*KD
    unsigned short* bbf = qbf + (size_t)Q * KD;                        // Npad*KD
    float* fbase  = (float*)(bbf + (size_t)Npad * KD);
    float* q2     = fbase;                                             // Q
    float* b2     = q2 + Q;                                            // Npad
    float* cand   = b2 + Npad;                                         // NSPLIT*2*Q*3
    float* scores = cand + (size_t)NSPLIT * 2 * Q * 3;                 // Q
    float* out    = (float*)d_out;

    hipLaunchKernelGGL(q_prep_k, dim3(B * 16), dim3(256), 0, stream, emb, qbf);
    hipLaunchKernelGGL(prep2_k, dim3(((Npad + Q) * 64 + 255) / 256), dim3(256), 0, stream,
                       bank, qbf, bbf, b2, q2, Nbank, Npad, Q);
    hipLaunchKernelGGL(knn_mfma_k, dim3(Mtiles * NSPLIT), dim3(256), 0, stream,
                       qbf, bbf, q2, b2, cand, ntiles, Q);
    hipLaunchKernelGGL(scores_k, dim3((Q + 255) / 256), dim3(256), 0, stream, cand, scores, Q);
    hipLaunchKernelGGL(upsample_k, dim3((out_size + 255) / 256), dim3(256), 0, stream,
                       scores, out, out_size);
}

// Round 4
// 628.556 us; speedup vs baseline: 15.5916x; 1.1193x over previous
//
#include <hip/hip_runtime.h>
#include <math.h>

#define KD     768     // embedding dim
#define MT     128     // M tile (queries)
#define NT     128     // N tile (bank rows)
#define BK     64      // K chunk
#define NSPLIT 16      // bank splits per M tile
#define BIGF   3.0e38f

typedef __attribute__((ext_vector_type(8))) short bf16x8;
typedef __attribute__((ext_vector_type(4))) float f32x4;

__device__ __forceinline__ unsigned short f2bf(float f) {
    unsigned u = __float_as_uint(f);
    u += 0x7fffu + ((u >> 16) & 1u);          // round-to-nearest-even
    return (unsigned short)(u >> 16);
}
__device__ __forceinline__ float bf2f(unsigned short h) {
    return __uint_as_float(((unsigned)h) << 16);
}
__device__ __forceinline__ void ins3(float* t, float v) {
    float lo0 = fminf(t[0], v);
    float hi0 = fmaxf(t[0], v);
    float lo1 = fminf(t[1], hi0);
    float hi1 = fmaxf(t[1], hi0);
    float lo2 = fminf(t[2], hi1);
    t[0] = lo0; t[1] = lo1; t[2] = lo2;
}
__device__ __forceinline__ void async16(unsigned short* lds, const unsigned short* g) {
    __builtin_amdgcn_global_load_lds(
        (const __attribute__((address_space(1))) unsigned int*)g,
        (__attribute__((address_space(3))) unsigned int*)lds, 16, 0, 0);
}

// ---- emb [B][768][1024] -> qbf [B*1024][768] bf16 (LDS tile transpose) ----
__global__ void q_prep_k(const float* __restrict__ emb, unsigned short* __restrict__ qbf) {
    __shared__ float s[64][65];
    int b   = blockIdx.x >> 4;
    int hw0 = (blockIdx.x & 15) * 64;
    const float* src = emb + (size_t)b * KD * 1024;
    for (int e0 = 0; e0 < KD; e0 += 64) {
        __syncthreads();
        #pragma unroll
        for (int i = 0; i < 16; ++i) {
            int idx = threadIdx.x + i * 256;      // 0..4095
            int ee = idx >> 6, hh = idx & 63;
            s[ee][hh] = src[(size_t)(e0 + ee) * 1024 + hw0 + hh];
        }
        __syncthreads();
        #pragma unroll
        for (int i = 0; i < 16; ++i) {
            int idx = threadIdx.x + i * 256;
            int qq = idx >> 6, ee = idx & 63;
            qbf[((size_t)b * 1024 + hw0 + qq) * KD + e0 + ee] = f2bf(s[ee][qq]);
        }
    }
}

// ---- bank -> bbf bf16 (zero-padded) + b2 norms (BIGF pad) + q2 norms ----
__global__ void prep2_k(const float* __restrict__ bank, const unsigned short* __restrict__ qbf,
                        unsigned short* __restrict__ bbf, float* __restrict__ b2,
                        float* __restrict__ q2, int N, int Npad, int Q) {
    int gid = blockIdx.x * 256 + threadIdx.x;
    int row = gid >> 6, lane = gid & 63;
    if (row < Npad) {
        if (row < N) {
            float s = 0.f;
            #pragma unroll
            for (int i = 0; i < KD / 64; ++i) {
                float v = bank[(size_t)row * KD + lane + i * 64];
                unsigned short u = f2bf(v);
                float vb = bf2f(u);
                s = fmaf(vb, vb, s);
                bbf[(size_t)row * KD + lane + i * 64] = u;
            }
            #pragma unroll
            for (int off = 32; off; off >>= 1) s += __shfl_down(s, off, 64);
            if (lane == 0) b2[row] = s;
        } else {
            #pragma unroll
            for (int i = 0; i < KD / 64; ++i) bbf[(size_t)row * KD + lane + i * 64] = 0;
            if (lane == 0) b2[row] = BIGF;
        }
    } else {
        int q = row - Npad;
        if (q < Q) {
            float s = 0.f;
            #pragma unroll
            for (int i = 0; i < KD / 64; ++i) {
                float v = bf2f(qbf[(size_t)q * KD + lane + i * 64]);
                s = fmaf(v, v, s);
            }
            #pragma unroll
            for (int off = 32; off; off >>= 1) s += __shfl_down(s, off, 64);
            if (lane == 0) q2[q] = s;
        }
    }
}

// ---- main: bf16 MFMA distance GEMM + fused per-row top-3 ----
// grid = 1024. Block->XCD is bx%8 (round robin). Decode so each XCD owns
// 16 M-tiles x 8 splits: per-XCD L2 hot set = A 3.1 MB (resident, re-read
// 10x from L2) + B ~1.6 MB streaming. Each CU's 4 blocks share one sp ->
// identical B-tile stream (L2/L1 hits on staging).
__global__ __launch_bounds__(256, 4)
void knn_mfma_k(const unsigned short* __restrict__ qbf, const unsigned short* __restrict__ bbf,
                const float* __restrict__ q2g, const float* __restrict__ b2g,
                float* __restrict__ cand, int ntiles, int Q) {
    __shared__ unsigned short stage[2][MT * BK];   // A tile | B tile, XOR-swizzled (32768 B)

    const int tid  = threadIdx.x;
    const int lane = tid & 63;
    const int quad = lane >> 4;
    const int l15  = lane & 15;
    const int wid  = tid >> 6;
    const int wm   = wid & 1;
    const int wn   = wid >> 1;

    const int bx   = blockIdx.x;
    const int xcd  = bx & 7;
    const int j    = bx >> 3;            // 0..127
    const int sp   = (j & 7) + 8 * (xcd >> 2);
    const int mt   = (xcd & 3) * 16 + (j >> 3);
    const int Mbase = mt * MT;

    float q2c[16];
    #pragma unroll
    for (int mi = 0; mi < 4; ++mi)
        #pragma unroll
        for (int r = 0; r < 4; ++r)
            q2c[mi * 4 + r] = q2g[Mbase + 64 * wm + 16 * mi + 4 * quad + r];

    float top3[48];
    #pragma unroll
    for (int i = 0; i < 48; ++i) top3[i] = BIGF;

    const int xr = l15 & 7;

    for (int nt = sp; nt < ntiles; nt += NSPLIT) {
        const size_t nbase = (size_t)nt * NT;
        f32x4 acc[4][4];
        #pragma unroll
        for (int a = 0; a < 4; ++a)
            #pragma unroll
            for (int b = 0; b < 4; ++b) acc[a][b] = (f32x4){0.f, 0.f, 0.f, 0.f};

        const unsigned short* gA = qbf + (size_t)Mbase * KD;
        const unsigned short* gB = bbf + nbase * KD;

        for (int kc = 0; kc < KD / BK; ++kc) {
            const int k0 = kc * BK;
            __syncthreads();
            // stage A/B: 1024 slots of 16B each; slot s=(m,g) holds k-group g^(m&7)
            #pragma unroll
            for (int i = 0; i < 4; ++i) {
                int s = tid + i * 256;
                int m = s >> 3, g = s & 7;
                int G = g ^ (m & 7);
                async16(&stage[0][s * 8], gA + (size_t)m * KD + k0 + G * 8);
            }
            #pragma unroll
            for (int i = 0; i < 4; ++i) {
                int s = tid + i * 256;
                int m = s >> 3, g = s & 7;
                int G = g ^ (m & 7);
                async16(&stage[1][s * 8], gB + (size_t)m * KD + k0 + G * 8);
            }
            __syncthreads();
            #pragma unroll
            for (int ks = 0; ks < 2; ++ks) {
                bf16x8 af[4], bfr[4];
                const int Gk = ks * 4 + quad;
                const int col = ((Gk ^ xr) << 3);
                #pragma unroll
                for (int mi = 0; mi < 4; ++mi) {
                    int row = 64 * wm + 16 * mi + l15;
                    af[mi] = *(const bf16x8*)&stage[0][row * BK + col];
                }
                #pragma unroll
                for (int ni = 0; ni < 4; ++ni) {
                    int row = 64 * wn + 16 * ni + l15;
                    bfr[ni] = *(const bf16x8*)&stage[1][row * BK + col];
                }
                #pragma unroll
                for (int mi = 0; mi < 4; ++mi)
                    #pragma unroll
                    for (int ni = 0; ni < 4; ++ni)
                        acc[mi][ni] = __builtin_amdgcn_mfma_f32_16x16x32_bf16(
                            af[mi], bfr[ni], acc[mi][ni], 0, 0, 0);
            }
        }
        // epilogue: d2 = q2 + b2 - 2*dot, per-row top3 (C layout: col=l15, row=4*quad+reg)
        #pragma unroll
        for (int ni = 0; ni < 4; ++ni) {
            float b2v = b2g[nbase + 64 * wn + 16 * ni + l15];
            #pragma unroll
            for (int mi = 0; mi < 4; ++mi)
                #pragma unroll
                for (int r = 0; r < 4; ++r) {
                    float d2 = q2c[mi * 4 + r] + b2v - 2.0f * acc[mi][ni][r];
                    ins3(&top3[(mi * 4 + r) * 3], d2);
                }
        }
    }

    // merge the 16 column-partials per query row via shfl_xor butterfly
    #pragma unroll
    for (int mi = 0; mi < 4; ++mi)
        #pragma unroll
        for (int r = 0; r < 4; ++r) {
            float a0 = top3[(mi * 4 + r) * 3 + 0];
            float a1 = top3[(mi * 4 + r) * 3 + 1];
            float a2 = top3[(mi * 4 + r) * 3 + 2];
            #pragma unroll
            for (int off = 1; off < 16; off <<= 1) {
                float b0 = __shfl_xor(a0, off, 64);
                float b1 = __shfl_xor(a1, off, 64);
                float b2v = __shfl_xor(a2, off, 64);
                float t[3] = {a0, a1, a2};
                ins3(t, b0); ins3(t, b1); ins3(t, b2v);
                a0 = t[0]; a1 = t[1]; a2 = t[2];
            }
            if (l15 == 0) {
                int row = Mbase + 64 * wm + 16 * mi + 4 * quad + r;
                float* o = cand + ((size_t)(sp * 2 + wn) * Q + row) * 3;
                o[0] = a0; o[1] = a1; o[2] = a2;
            }
        }
}

// ---- merge 32 split-partials -> mean sqrt distance ----
__global__ void scores_k(const float* __restrict__ cand, float* __restrict__ scores, int Q) {
    int idx = blockIdx.x * blockDim.x + threadIdx.x;
    if (idx >= Q) return;
    float best[3] = {BIGF, BIGF, BIGF};
    for (int sp = 0; sp < NSPLIT * 2; sp++) {
        const float* c = cand + ((size_t)sp * Q + idx) * 3;
        ins3(best, c[0]); ins3(best, c[1]); ins3(best, c[2]);
    }
    float s = (sqrtf(fmaxf(best[0], 1e-12f)) +
               sqrtf(fmaxf(best[1], 1e-12f)) +
               sqrtf(fmaxf(best[2], 1e-12f))) * (1.f / 3.f);
    scores[idx] = s;
}

// ---- bilinear x16 upsample, half-pixel, edge clamp ----
__global__ void upsample_k(const float* __restrict__ scores, float* __restrict__ out, int total) {
    int idx = blockIdx.x * blockDim.x + threadIdx.x;
    if (idx >= total) return;
    int x = idx & 511;
    int y = (idx >> 9) & 511;
    int b = idx >> 18;
    float sx = (x + 0.5f) * (1.f / 16.f) - 0.5f;
    float sy = (y + 0.5f) * (1.f / 16.f) - 0.5f;
    int x0 = (int)floorf(sx);
    int y0 = (int)floorf(sy);
    float wx = sx - (float)x0;
    float wy = sy - (float)y0;
    int x0c = min(max(x0, 0), 31), x1c = min(max(x0 + 1, 0), 31);
    int y0c = min(max(y0, 0), 31), y1c = min(max(y0 + 1, 0), 31);
    const float* sb = scores + (size_t)b * 1024;
    float v00 = sb[y0c * 32 + x0c], v01 = sb[y0c * 32 + x1c];
    float v10 = sb[y1c * 32 + x0c], v11 = sb[y1c * 32 + x1c];
    float v0 = v00 + wx * (v01 - v00);
    float v1 = v10 + wx * (v11 - v10);
    out[idx] = v0 + wy * (v1 - v0);
}

extern "C" void kernel_launch(void* const* d_in, const int* in_sizes, int n_in,
                              void* d_out, int out_size, void* d_ws, size_t ws_size,
                              hipStream_t stream) {
    const float* emb  = (const float*)d_in[0];
    const float* bank = (const float*)d_in[1];
    const int Q      = in_sizes[0] / KD;             // 8192
    const int B      = Q / 1024;                     // 8
    const int Nbank  = in_sizes[1] / KD;             // 20000
    const int ntiles = (Nbank + NT - 1) / NT;        // 157
    const int Npad   = ntiles * NT;                  // 20096
    const int Mtiles = Q / MT;                       // 64

    // workspace layout
    unsigned short* qbf = (unsigned short*)d_ws;                       // Q*KD
    unsigned short* bbf = qbf + (size_t)Q * KD;                        // Npad*KD
    float* fbase  = (float*)(bbf + (size_t)Npad * KD);
    float* q2     = fbase;                                             // Q
    float* b2     = q2 + Q;                                            // Npad
    float* cand   = b2 + Npad;                                         // NSPLIT*2*Q*3
    float* scores = cand + (size_t)NSPLIT * 2 * Q * 3;                 // Q
    float* out    = (float*)d_out;

    hipLaunchKernelGGL(q_prep_k, dim3(B * 16), dim3(256), 0, stream, emb, qbf);
    hipLaunchKernelGGL(prep2_k, dim3(((Npad + Q) * 64 + 255) / 256), dim3(256), 0, stream,
                       bank, qbf, bbf, b2, q2, Nbank, Npad, Q);
    hipLaunchKernelGGL(knn_mfma_k, dim3(Mtiles * NSPLIT), dim3(256), 0, stream,
                       qbf, bbf, q2, b2, cand, ntiles, Q);
    hipLaunchKernelGGL(scores_k, dim3((Q + 255) / 256), dim3(256), 0, stream, cand, scores, Q);
    hipLaunchKernelGGL(upsample_k, dim3((out_size + 255) / 256), dim3(256), 0, stream,
                       scores, out, out_size);
}

// Round 5
// 606.262 us; speedup vs baseline: 16.1649x; 1.0368x over previous
//
#include <hip/hip_runtime.h>
#include <math.h>

#define KD     768     // embedding dim
#define MT     128     // M tile (queries)
#define NT     128     // N tile (bank rows)
#define BK     64      // K chunk
#define NSPLIT 16      // bank splits per M tile
#define BIGF   3.0e38f

typedef __attribute__((ext_vector_type(8))) short bf16x8;
typedef __attribute__((ext_vector_type(4))) float f32x4;

__device__ __forceinline__ unsigned short f2bf(float f) {
    unsigned u = __float_as_uint(f);
    u += 0x7fffu + ((u >> 16) & 1u);          // round-to-nearest-even
    return (unsigned short)(u >> 16);
}
__device__ __forceinline__ float bf2f(unsigned short h) {
    return __uint_as_float(((unsigned)h) << 16);
}
__device__ __forceinline__ void ins3(float* t, float v) {
    float lo0 = fminf(t[0], v);
    float hi0 = fmaxf(t[0], v);
    float lo1 = fminf(t[1], hi0);
    float hi1 = fmaxf(t[1], hi0);
    float lo2 = fminf(t[2], hi1);
    t[0] = lo0; t[1] = lo1; t[2] = lo2;
}
__device__ __forceinline__ void async16(unsigned short* lds, const unsigned short* g) {
    __builtin_amdgcn_global_load_lds(
        (const __attribute__((address_space(1))) unsigned int*)g,
        (__attribute__((address_space(3))) unsigned int*)lds, 16, 0, 0);
}

// ---- emb [B][768][1024] -> qbf [B*1024][768] bf16 (LDS tile transpose) ----
__global__ void q_prep_k(const float* __restrict__ emb, unsigned short* __restrict__ qbf) {
    __shared__ float s[64][65];
    int b   = blockIdx.x >> 4;
    int hw0 = (blockIdx.x & 15) * 64;
    const float* src = emb + (size_t)b * KD * 1024;
    for (int e0 = 0; e0 < KD; e0 += 64) {
        __syncthreads();
        #pragma unroll
        for (int i = 0; i < 16; ++i) {
            int idx = threadIdx.x + i * 256;      // 0..4095
            int ee = idx >> 6, hh = idx & 63;
            s[ee][hh] = src[(size_t)(e0 + ee) * 1024 + hw0 + hh];
        }
        __syncthreads();
        #pragma unroll
        for (int i = 0; i < 16; ++i) {
            int idx = threadIdx.x + i * 256;
            int qq = idx >> 6, ee = idx & 63;
            qbf[((size_t)b * 1024 + hw0 + qq) * KD + e0 + ee] = f2bf(s[ee][qq]);
        }
    }
}

// ---- bank -> bbf bf16 (zero-padded) + b2 norms (BIGF pad) + q2 norms ----
__global__ void prep2_k(const float* __restrict__ bank, const unsigned short* __restrict__ qbf,
                        unsigned short* __restrict__ bbf, float* __restrict__ b2,
                        float* __restrict__ q2, int N, int Npad, int Q) {
    int gid = blockIdx.x * 256 + threadIdx.x;
    int row = gid >> 6, lane = gid & 63;
    if (row < Npad) {
        if (row < N) {
            float s = 0.f;
            #pragma unroll
            for (int i = 0; i < KD / 64; ++i) {
                float v = bank[(size_t)row * KD + lane + i * 64];
                unsigned short u = f2bf(v);
                float vb = bf2f(u);
                s = fmaf(vb, vb, s);
                bbf[(size_t)row * KD + lane + i * 64] = u;
            }
            #pragma unroll
            for (int off = 32; off; off >>= 1) s += __shfl_down(s, off, 64);
            if (lane == 0) b2[row] = s;
        } else {
            #pragma unroll
            for (int i = 0; i < KD / 64; ++i) bbf[(size_t)row * KD + lane + i * 64] = 0;
            if (lane == 0) b2[row] = BIGF;
        }
    } else {
        int q = row - Npad;
        if (q < Q) {
            float s = 0.f;
            #pragma unroll
            for (int i = 0; i < KD / 64; ++i) {
                float v = bf2f(qbf[(size_t)q * KD + lane + i * 64]);
                s = fmaf(v, v, s);
            }
            #pragma unroll
            for (int off = 32; off; off >>= 1) s += __shfl_down(s, off, 64);
            if (lane == 0) q2[q] = s;
        }
    }
}

__device__ __forceinline__ void stage_chunk(unsigned short (*stage)[MT * BK],
                                            const unsigned short* gA, const unsigned short* gB,
                                            int k0, int tid) {
    // 1024 slots of 16B per operand; slot s=(m,g) holds k-group g^(m&7) (XOR swizzle)
    #pragma unroll
    for (int i = 0; i < 4; ++i) {
        int s = tid + i * 256;
        int m = s >> 3, g = s & 7;
        int G = g ^ (m & 7);
        async16(&stage[0][s * 8], gA + (size_t)m * KD + k0 + G * 8);
    }
    #pragma unroll
    for (int i = 0; i < 4; ++i) {
        int s = tid + i * 256;
        int m = s >> 3, g = s & 7;
        int G = g ^ (m & 7);
        async16(&stage[1][s * 8], gB + (size_t)m * KD + k0 + G * 8);
    }
}

__device__ __forceinline__ void mfma_chunk(const unsigned short (*stage)[MT * BK],
                                           f32x4 acc[4][4], int wm, int wn,
                                           int l15, int quad, int xr) {
    #pragma unroll
    for (int ks = 0; ks < 2; ++ks) {
        bf16x8 af[4], bfr[4];
        const int Gk = ks * 4 + quad;
        const int col = ((Gk ^ xr) << 3);
        #pragma unroll
        for (int mi = 0; mi < 4; ++mi) {
            int row = 64 * wm + 16 * mi + l15;
            af[mi] = *(const bf16x8*)&stage[0][row * BK + col];
        }
        #pragma unroll
        for (int ni = 0; ni < 4; ++ni) {
            int row = 64 * wn + 16 * ni + l15;
            bfr[ni] = *(const bf16x8*)&stage[1][row * BK + col];
        }
        #pragma unroll
        for (int mi = 0; mi < 4; ++mi)
            #pragma unroll
            for (int ni = 0; ni < 4; ++ni)
                acc[mi][ni] = __builtin_amdgcn_mfma_f32_16x16x32_bf16(
                    af[mi], bfr[ni], acc[mi][ni], 0, 0, 0);
    }
}

// epilogue: s = b2 - 2*dot (q2 added later; per-row constant preserves order)
__device__ __forceinline__ void do_epilogue(const f32x4 acc[4][4], const float b2v[4],
                                            float* top3) {
    #pragma unroll
    for (int ni = 0; ni < 4; ++ni)
        #pragma unroll
        for (int mi = 0; mi < 4; ++mi)
            #pragma unroll
            for (int r = 0; r < 4; ++r) {
                float s = fmaf(-2.0f, acc[mi][ni][r], b2v[ni]);
                ins3(&top3[(mi * 4 + r) * 3], s);
            }
}

// ---- main: bf16 MFMA distance GEMM + fused per-row top-3 ----
// grid = 1024, bx%8 = XCD. Decode: same-sp blocks are 16 consecutive bx on
// 16 distinct CUs (near-lockstep -> B tile fetched ~1x/XCD); the 4 blocks
// sharing a CU share the SAME A tile (L1 hits on A staging). Per-XCD L2:
// A 16 tiles = 3.07 MB resident, B 8 streams.
__global__ __launch_bounds__(256, 4)
void knn_mfma_k(const unsigned short* __restrict__ qbf, const unsigned short* __restrict__ bbf,
                const float* __restrict__ b2g, float* __restrict__ cand,
                int ntiles, int Q) {
    __shared__ unsigned short stage[2][MT * BK];   // A tile | B tile (32768 B)

    const int tid  = threadIdx.x;
    const int lane = tid & 63;
    const int quad = lane >> 4;
    const int l15  = lane & 15;
    const int wid  = tid >> 6;
    const int wm   = wid & 1;
    const int wn   = wid >> 1;

    const int bx   = blockIdx.x;
    const int xcd  = bx & 7;
    const int j    = bx >> 3;                  // 0..127
    const int sp   = (j >> 4) + 8 * (xcd >> 2);
    const int mt   = (xcd & 3) * 16 + (j & 15);
    const int Mbase = mt * MT;

    float top3[48];
    #pragma unroll
    for (int i = 0; i < 48; ++i) top3[i] = BIGF;

    const int xr = l15 & 7;
    const unsigned short* gA = qbf + (size_t)Mbase * KD;

    f32x4 acc[4][4];
    float b2v[4];
    bool first = true;

    for (int nt = sp; nt < ntiles; nt += NSPLIT) {
        const size_t nbase = (size_t)nt * NT;
        const unsigned short* gB = bbf + nbase * KD;

        __syncthreads();                       // prior chunk reads complete
        stage_chunk(stage, gA, gB, 0, tid);    // kc0 staging in flight
        float t0 = b2g[nbase + 64 * wn + 0  + l15];
        float t1 = b2g[nbase + 64 * wn + 16 + l15];
        float t2 = b2g[nbase + 64 * wn + 32 + l15];
        float t3 = b2g[nbase + 64 * wn + 48 + l15];
        if (!first) do_epilogue(acc, b2v, top3);   // overlaps staging latency
        first = false;
        b2v[0] = t0; b2v[1] = t1; b2v[2] = t2; b2v[3] = t3;
        #pragma unroll
        for (int a = 0; a < 4; ++a)
            #pragma unroll
            for (int b = 0; b < 4; ++b) acc[a][b] = (f32x4){0.f, 0.f, 0.f, 0.f};
        __syncthreads();                       // kc0 loads complete
        mfma_chunk(stage, acc, wm, wn, l15, quad, xr);

        for (int kc = 1; kc < KD / BK; ++kc) {
            __syncthreads();
            stage_chunk(stage, gA, gB, kc * BK, tid);
            __syncthreads();
            mfma_chunk(stage, acc, wm, wn, l15, quad, xr);
        }
    }
    do_epilogue(acc, b2v, top3);

    // merge the 16 column-partials per query row via shfl_xor butterfly
    #pragma unroll
    for (int mi = 0; mi < 4; ++mi)
        #pragma unroll
        for (int r = 0; r < 4; ++r) {
            float a0 = top3[(mi * 4 + r) * 3 + 0];
            float a1 = top3[(mi * 4 + r) * 3 + 1];
            float a2 = top3[(mi * 4 + r) * 3 + 2];
            #pragma unroll
            for (int off = 1; off < 16; off <<= 1) {
                float b0 = __shfl_xor(a0, off, 64);
                float b1 = __shfl_xor(a1, off, 64);
                float b2x = __shfl_xor(a2, off, 64);
                float t[3] = {a0, a1, a2};
                ins3(t, b0); ins3(t, b1); ins3(t, b2x);
                a0 = t[0]; a1 = t[1]; a2 = t[2];
            }
            if (l15 == 0) {
                int row = Mbase + 64 * wm + 16 * mi + 4 * quad + r;
                float* o = cand + ((size_t)(sp * 2 + wn) * Q + row) * 3;
                o[0] = a0; o[1] = a1; o[2] = a2;
            }
        }
}

// ---- merge 32 split-partials (s = b2-2dot) -> d2 = q2+s -> mean sqrt ----
__global__ void scores_k(const float* __restrict__ cand, const float* __restrict__ q2g,
                         float* __restrict__ scores, int Q) {
    int idx = blockIdx.x * blockDim.x + threadIdx.x;
    if (idx >= Q) return;
    float best[3] = {BIGF, BIGF, BIGF};
    for (int sp = 0; sp < NSPLIT * 2; sp++) {
        const float* c = cand + ((size_t)sp * Q + idx) * 3;
        ins3(best, c[0]); ins3(best, c[1]); ins3(best, c[2]);
    }
    float q2 = q2g[idx];
    float s = (sqrtf(fmaxf(q2 + best[0], 1e-12f)) +
               sqrtf(fmaxf(q2 + best[1], 1e-12f)) +
               sqrtf(fmaxf(q2 + best[2], 1e-12f))) * (1.f / 3.f);
    scores[idx] = s;
}

// ---- bilinear x16 upsample, half-pixel, edge clamp ----
__global__ void upsample_k(const float* __restrict__ scores, float* __restrict__ out, int total) {
    int idx = blockIdx.x * blockDim.x + threadIdx.x;
    if (idx >= total) return;
    int x = idx & 511;
    int y = (idx >> 9) & 511;
    int b = idx >> 18;
    float sx = (x + 0.5f) * (1.f / 16.f) - 0.5f;
    float sy = (y + 0.5f) * (1.f / 16.f) - 0.5f;
    int x0 = (int)floorf(sx);
    int y0 = (int)floorf(sy);
    float wx = sx - (float)x0;
    float wy = sy - (float)y0;
    int x0c = min(max(x0, 0), 31), x1c = min(max(x0 + 1, 0), 31);
    int y0c = min(max(y0, 0), 31), y1c = min(max(y0 + 1, 0), 31);
    const float* sb = scores + (size_t)b * 1024;
    float v00 = sb[y0c * 32 + x0c], v01 = sb[y0c * 32 + x1c];
    float v10 = sb[y1c * 32 + x0c], v11 = sb[y1c * 32 + x1c];
    float v0 = v00 + wx * (v01 - v00);
    float v1 = v10 + wx * (v11 - v10);
    out[idx] = v0 + wy * (v1 - v0);
}

extern "C" void kernel_launch(void* const* d_in, const int* in_sizes, int n_in,
                              void* d_out, int out_size, void* d_ws, size_t ws_size,
                              hipStream_t stream) {
    const float* emb  = (const float*)d_in[0];
    const float* bank = (const float*)d_in[1];
    const int Q      = in_sizes[0] / KD;             // 8192
    const int B      = Q / 1024;                     // 8
    const int Nbank  = in_sizes[1] / KD;             // 20000
    const int ntiles = (Nbank + NT - 1) / NT;        // 157
    const int Npad   = ntiles * NT;                  // 20096
    const int Mtiles = Q / MT;                       // 64

    // workspace layout
    unsigned short* qbf = (unsigned short*)d_ws;                       // Q*KD
    unsigned short* bbf = qbf + (size_t)Q * KD;                        // Npad*KD
    float* fbase  = (float*)(bbf + (size_t)Npad * KD);
    float* q2     = fbase;                                             // Q
    float* b2     = q2 + Q;                                            // Npad
    float* cand   = b2 + Npad;                                         // NSPLIT*2*Q*3
    float* scores = cand + (size_t)NSPLIT * 2 * Q * 3;                 // Q
    float* out    = (float*)d_out;

    hipLaunchKernelGGL(q_prep_k, dim3(B * 16), dim3(256), 0, stream, emb, qbf);
    hipLaunchKernelGGL(prep2_k, dim3(((Npad + Q) * 64 + 255) / 256), dim3(256), 0, stream,
                       bank, qbf, bbf, b2, q2, Nbank, Npad, Q);
    hipLaunchKernelGGL(knn_mfma_k, dim3(Mtiles * NSPLIT), dim3(256), 0, stream,
                       qbf, bbf, b2, cand, ntiles, Q);
    hipLaunchKernelGGL(scores_k, dim3((Q + 255) / 256), dim3(256), 0, stream,
                       cand, q2, scores, Q);
    hipLaunchKernelGGL(upsample_k, dim3((out_size + 255) / 256), dim3(256), 0, stream,
                       scores, out, out_size);
}